// Round 5
// baseline (446.358 us; speedup 1.0000x reference)
//
#include <hip/hip_runtime.h>
#include <hip/hip_bf16.h>
#include <stdint.h>

#define N_TOK 16384
#define DMODEL 1024
#define EXP 16
#define CAP 4096
#define TT 32768          // N_TOK * K (K=2)

typedef __bf16 bf16x8 __attribute__((ext_vector_type(8)));
typedef __bf16 bf16x4 __attribute__((ext_vector_type(4)));
typedef float  f32x4  __attribute__((ext_vector_type(4)));

__device__ __forceinline__ void gl_lds16(const void* g, void* s) {
  __builtin_amdgcn_global_load_lds(
      (__attribute__((address_space(1))) void*)(void*)g,
      (__attribute__((address_space(3))) void*)s, 16, 0, 0);
}

__device__ __forceinline__ float bfbits2f(unsigned short u) {
  return __uint_as_float(((unsigned)u) << 16);
}

#define FENCE asm volatile("" ::: "memory")
#define BAR() do { FENCE; __builtin_amdgcn_s_barrier(); FENCE; } while (0)

// ------------- transpose + convert W1/W2 to bf16 [e][n][k] -------------
__global__ __launch_bounds__(256) void convw_kernel(const float* __restrict__ W1,
                                                    const float* __restrict__ W2,
                                                    __bf16* __restrict__ W1bt,
                                                    __bf16* __restrict__ W2bt) {
  __shared__ float tile[64][65];
  int b = blockIdx.x;
  int tx = b & 15;           // col-tile (k dim of source)
  int ty = (b >> 4) & 15;    // row-tile
  int e  = (b >> 8) & 15;
  int which = (b >> 12) & 1;
  const float* src = (which ? W2 : W1) + (size_t)e * DMODEL * DMODEL;
  __bf16*      dst = (which ? W2bt : W1bt) + (size_t)e * DMODEL * DMODEL;
  int t = threadIdx.x;
  int r = t >> 2;             // 0..63
  int cs = (t & 3) * 16;      // 0,16,32,48
  int r0 = ty * 64, c0 = tx * 64;
  #pragma unroll
  for (int i = 0; i < 16; i += 4) {
    float4 v = *(const float4*)(src + (size_t)(r0 + r) * DMODEL + c0 + cs + i);
    tile[r][cs + i + 0] = v.x; tile[r][cs + i + 1] = v.y;
    tile[r][cs + i + 2] = v.z; tile[r][cs + i + 3] = v.w;
  }
  __syncthreads();
  bf16x8 o1, o2;
  #pragma unroll
  for (int i = 0; i < 8; i++) o1[i] = (__bf16)tile[cs + i][r];
  #pragma unroll
  for (int i = 0; i < 8; i++) o2[i] = (__bf16)tile[cs + 8 + i][r];
  *(bf16x8*)(dst + (size_t)(c0 + r) * DMODEL + r0 + cs)     = o1;
  *(bf16x8*)(dst + (size_t)(c0 + r) * DMODEL + r0 + cs + 8) = o2;
}

// ------- gate: logits via LDS-staged gw (fp32), fused X->bf16 -------
__global__ __launch_bounds__(256) void gate_kernel(const float* __restrict__ x,
                                                   const float* __restrict__ gw,
                                                   const float* __restrict__ gb,
                                                   const float* __restrict__ rw,
                                                   const float* __restrict__ rb,
                                                   int* __restrict__ idxo,
                                                   float* __restrict__ sco,
                                                   __bf16* __restrict__ Xb) {
  __shared__ float gws[512 * 17];   // 34816 B
  __shared__ float rws[512];        //  2048 B
  int tid = threadIdx.x;
  int w = tid >> 6, lane = tid & 63;
  int n = blockIdx.x * 4 + w;
  const float* xr = x + (size_t)n * DMODEL;
  __bf16* xbr = Xb + (size_t)n * DMODEL;

  float acc[17];
  #pragma unroll
  for (int j = 0; j < 17; j++) acc[j] = 0.f;

  for (int c = 0; c < 2; c++) {
    int c0 = c * 512;
    __syncthreads();   // protect previous chunk's reads before overwrite
    for (int i = tid; i < 512 * 16; i += 256)
      gws[(i >> 4) * 17 + (i & 15)] = gw[c0 * 16 + i];
    for (int i = tid; i < 512; i += 256)
      rws[i] = rw[c0 + i];
    __syncthreads();

    float xv[8];
    #pragma unroll
    for (int u = 0; u < 8; u++) xv[u] = xr[c0 + u * 64 + lane];
    #pragma unroll
    for (int u = 0; u < 8; u++) xbr[c0 + u * 64 + lane] = (__bf16)xv[u];
    #pragma unroll
    for (int u = 0; u < 8; u++) {
      int dl = u * 64 + lane;
      const float* g = &gws[dl * 17];
      #pragma unroll
      for (int j = 0; j < 16; j++) acc[j] += xv[u] * g[j];
      acc[16] += xv[u] * rws[dl];
    }
  }

  #pragma unroll
  for (int o = 1; o < 64; o <<= 1) {
    #pragma unroll
    for (int j = 0; j < 17; j++) acc[j] += __shfl_xor(acc[j], o);
  }
  if (lane == 0) {
    float rv = acc[16] + rb[0];
    bool g1 = rv > 0.f;
    float c[8];
    #pragma unroll
    for (int j = 0; j < 8; j++)
      c[j] = (g1 ? acc[j] + gb[j] : acc[8 + j] + gb[8 + j]);
    int i1 = 0; float v1 = c[0];
    #pragma unroll
    for (int j = 1; j < 8; j++) { if (c[j] > v1) { v1 = c[j]; i1 = j; } }
    int i2 = -1; float v2 = -3.4e38f;
    #pragma unroll
    for (int j = 0; j < 8; j++) { if (j != i1 && c[j] > v2) { v2 = c[j]; i2 = j; } }
    float e2 = expf(v2 - v1);
    float den = 1.f + e2;
    int base = g1 ? 0 : 8;
    idxo[2 * n] = base + i1; idxo[2 * n + 1] = base + i2;
    sco[2 * n] = 1.f / den;  sco[2 * n + 1] = e2 / den;
  }
}

// ------------- scan: t-ordered per-expert ranks, rowlists, offsets -------------
__global__ __launch_bounds__(1024) void scan_kernel(const int* __restrict__ idx,
                                                    float* __restrict__ sco,
                                                    int* __restrict__ rowlist,
                                                    int* __restrict__ cnt,
                                                    int* __restrict__ off) {
  __shared__ int hist[16 * 1024];   // 64 KB
  int tid = threadIdx.x;
  #pragma unroll
  for (int e = 0; e < 16; e++) hist[e * 1024 + tid] = 0;
  __syncthreads();
  int base = tid * 32;
  for (int i = 0; i < 32; i++) {
    int e = idx[base + i];
    hist[e * 1024 + tid]++;
  }
  __syncthreads();
  int w = tid >> 6, lane = tid & 63;
  {
    int e = w;  // 16 waves == 16 experts
    int running = 0;
    for (int cch = 0; cch < 16; cch++) {
      int v = hist[e * 1024 + cch * 64 + lane];
      int orig = v;
      #pragma unroll
      for (int o = 1; o < 64; o <<= 1) {
        int nv = __shfl_up(v, o);
        if (lane >= o) v += nv;
      }
      hist[e * 1024 + cch * 64 + lane] = running + v - orig;  // exclusive base
      running += __shfl(v, 63);
    }
    if (lane == 0) cnt[e] = running;   // raw count
  }
  __syncthreads();
  if (tid == 0) {
    int o = 0;
    for (int e = 0; e < 16; e++) {
      int c = cnt[e]; if (c > CAP) c = CAP;
      off[e] = o; cnt[e] = c; o += c;
    }
  }
  __syncthreads();
  for (int i = 0; i < 32; i++) {
    int t = base + i;
    int e = idx[t];
    int r = hist[e * 1024 + tid]++;
    if (r < CAP) rowlist[e * CAP + r] = t;
    else sco[t] = 0.f;   // dropped slot contributes zero
  }
}

// ------- grouped GEMM: 256x256x64, 16 waves (64x64/wave), 2-phase schedule -------
// LDS layout/swizzle identical to R4 (conflict-free measured). Staging 2 tiles
// ahead: stA(t+2)@P1, stB(t+2)@P2; steady-state vmcnt(4) == tile t+1 landed.
#define GBM 256
#define GBN 256
#define GBK 64
#define NKT (DMODEL / GBK)   // 16 K-steps

__global__ __launch_bounds__(1024, 4) void moe_gemm(const __bf16* __restrict__ A,
                                                    const __bf16* __restrict__ Bt,
                                                    const float* __restrict__ bias,
                                                    __bf16* __restrict__ out,
                                                    const int* __restrict__ rowlist,
                                                    const int* __restrict__ cnt,
                                                    const int* __restrict__ off,
                                                    int mode) {
  __shared__ char lds[131072];
  int bx = blockIdx.x;
  int em = (bx & 7) * 32 + (bx >> 3);   // XCD-aware bijective swizzle (256%8==0)
  int e  = em >> 4;
  int m0 = (em & 15) * GBM;
  int ce = cnt[e];
  if (m0 >= ce) return;
  int n0 = blockIdx.y * GBN;
  int oe = off[e];
  int tid = threadIdx.x;

  // staging source pointers [j]: 1024 threads x 2 granules cover a 32KB tile
  const __bf16* aP[2];
  const __bf16* bP[2];
  #pragma unroll
  for (int j = 0; j < 2; j++) {
    int c = j * 1024 + tid;
    int srow = c >> 3;                  // 0..255
    int gsrc = (c & 7) ^ (srow & 7);    // pre-swizzled source granule
    int rr = m0 + srow; if (rr > ce - 1) rr = ce - 1;
    size_t arow;
    if (mode == 0) arow = (size_t)(rowlist[e * CAP + rr] >> 1);  // token id
    else           arow = (size_t)(oe + rr);                     // h row
    aP[j] = A + arow * DMODEL + gsrc * 8;
    bP[j] = Bt + (size_t)e * DMODEL * DMODEL + (size_t)(n0 + srow) * DMODEL + gsrc * 8;
  }

  int w = tid >> 6, lane = tid & 63;
  int wr = (w >> 2) * 64;     // wave M-offset (4 groups of 64)
  int wc = (w & 3) * 64;      // wave N-offset
  int fr = lane & 15, fg = lane >> 4;

  int aRd = wr * 128 + fr * 128;
  int bRd = 65536 + wc * 128 + fr * 128;
  int gk0 = ((fg)     ^ (fr & 7)) * 16;
  int gk1 = ((4 | fg) ^ (fr & 7)) * 16;

  f32x4 acc[4][4];
  #pragma unroll
  for (int mi = 0; mi < 4; mi++)
    #pragma unroll
    for (int ni = 0; ni < 4; ni++)
      #pragma unroll
      for (int l = 0; l < 4; l++) acc[mi][ni][l] = 0.f;

  auto stA = [&](int s) {
    char* dst = lds + (s & 1) * 32768;
    gl_lds16(aP[0] + s * 64, dst + (size_t)tid * 16);
    gl_lds16(aP[1] + s * 64, dst + (size_t)(1024 + tid) * 16);
  };
  auto stB = [&](int s) {
    char* dst = lds + 65536 + (s & 1) * 32768;
    gl_lds16(bP[0] + s * 64, dst + (size_t)tid * 16);
    gl_lds16(bP[1] + s * 64, dst + (size_t)(1024 + tid) * 16);
  };

  // prologue: tiles 0 and 1 staged (8 instr); wait tile0 (4 newest remain)
  stA(0); stB(0); stA(1); stB(1);
  asm volatile("s_waitcnt vmcnt(4)" ::: "memory");
  BAR();

  bf16x8 afA[4][2], bq0[2][2], bq1[2][2];
  for (int t = 0; t < NKT; ++t) {
    const char* Ab = lds + (t & 1) * 32768 + aRd;
    const char* Bb = lds + (t & 1) * 32768 + bRd;

    // ---------------- P1: A frags + B(0,1); stage A(t+2); mfma acc[*][0-1] ----
    #pragma unroll
    for (int mi = 0; mi < 4; mi++) {
      afA[mi][0] = *(const bf16x8*)(Ab + mi * 2048 + gk0);
      afA[mi][1] = *(const bf16x8*)(Ab + mi * 2048 + gk1);
    }
    #pragma unroll
    for (int ni = 0; ni < 2; ni++) {
      bq0[ni][0] = *(const bf16x8*)(Bb + ni * 2048 + gk0);
      bq0[ni][1] = *(const bf16x8*)(Bb + ni * 2048 + gk1);
    }
    if (t <= 13) stA(t + 2);
    BAR();
    __builtin_amdgcn_s_setprio(1);
    #pragma unroll
    for (int kk = 0; kk < 2; kk++)
      #pragma unroll
      for (int mi = 0; mi < 4; mi++)
        #pragma unroll
        for (int ni = 0; ni < 2; ni++)
          acc[mi][ni] = __builtin_amdgcn_mfma_f32_16x16x32_bf16(afA[mi][kk], bq0[ni][kk], acc[mi][ni], 0, 0, 0);
    __builtin_amdgcn_s_setprio(0);
    BAR();

    // ---------------- P2: B(2,3); stage B(t+2); mfma acc[*][2-3] -------------
    #pragma unroll
    for (int ni = 0; ni < 2; ni++) {
      bq1[ni][0] = *(const bf16x8*)(Bb + (2 + ni) * 2048 + gk0);
      bq1[ni][1] = *(const bf16x8*)(Bb + (2 + ni) * 2048 + gk1);
    }
    if (t <= 13) stB(t + 2);
    BAR();
    __builtin_amdgcn_s_setprio(1);
    #pragma unroll
    for (int kk = 0; kk < 2; kk++)
      #pragma unroll
      for (int mi = 0; mi < 4; mi++)
        #pragma unroll
        for (int ni = 0; ni < 2; ni++)
          acc[mi][2 + ni] = __builtin_amdgcn_mfma_f32_16x16x32_bf16(afA[mi][kk], bq1[ni][kk], acc[mi][2 + ni], 0, 0, 0);
    __builtin_amdgcn_s_setprio(0);
    if (t <= 13)      asm volatile("s_waitcnt vmcnt(4)" ::: "memory");
    else if (t == 14) asm volatile("s_waitcnt vmcnt(0)" ::: "memory");
    BAR();
  }

  float bcol[4];
  #pragma unroll
  for (int ni = 0; ni < 4; ni++)
    bcol[ni] = bias[(size_t)e * DMODEL + n0 + wc + ni * 16 + fr];
  #pragma unroll
  for (int mi = 0; mi < 4; mi++) {
    #pragma unroll
    for (int r = 0; r < 4; r++) {
      int grow = m0 + wr + mi * 16 + fg * 4 + r;
      if (grow >= ce) continue;
      size_t orow = (mode == 0) ? (size_t)(oe + grow)
                                : (size_t)rowlist[e * CAP + grow];
      __bf16* op = out + orow * DMODEL + n0 + wc + fr;
      #pragma unroll
      for (int ni = 0; ni < 4; ni++) {
        float v = acc[mi][ni][r] + bcol[ni];
        if (mode == 0) v = fmaxf(v, 0.f);
        op[ni * 16] = (__bf16)v;
      }
    }
  }
}

// ---------------- combine: out[n] = s0*y[2n] + s1*y[2n+1] ----------------
__global__ __launch_bounds__(256) void combine_kernel(const __bf16* __restrict__ y,
                                                      const float* __restrict__ sco,
                                                      float* __restrict__ out) {
  int n = blockIdx.x;
  int d = threadIdx.x * 4;
  float s0 = sco[2 * n], s1 = sco[2 * n + 1];
  ushort4 a = *(const ushort4*)((const unsigned short*)(y + (size_t)(2 * n) * DMODEL + d));
  ushort4 b = *(const ushort4*)((const unsigned short*)(y + (size_t)(2 * n + 1) * DMODEL + d));
  float4 o;
  o.x = s0 * bfbits2f(a.x) + s1 * bfbits2f(b.x);
  o.y = s0 * bfbits2f(a.y) + s1 * bfbits2f(b.y);
  o.z = s0 * bfbits2f(a.z) + s1 * bfbits2f(b.z);
  o.w = s0 * bfbits2f(a.w) + s1 * bfbits2f(b.w);
  *(float4*)(out + (size_t)n * DMODEL + d) = o;
}

extern "C" void kernel_launch(void* const* d_in, const int* in_sizes, int n_in,
                              void* d_out, int out_size, void* d_ws, size_t ws_size,
                              hipStream_t stream) {
  const float* moe = (const float*)d_in[0];
  const float* gw  = (const float*)d_in[1];
  const float* gb  = (const float*)d_in[2];
  const float* rw  = (const float*)d_in[3];
  const float* rb  = (const float*)d_in[4];
  const float* W1  = (const float*)d_in[5];
  const float* b1  = (const float*)d_in[6];
  const float* W2  = (const float*)d_in[7];
  const float* b2  = (const float*)d_in[8];
  float* out = (float*)d_out;

  char* p = (char*)d_ws;
  __bf16* Xb   = (__bf16*)p; p += (size_t)N_TOK * DMODEL * 2;
  __bf16* W1bt = (__bf16*)p; p += (size_t)EXP * DMODEL * DMODEL * 2;
  __bf16* W2bt = (__bf16*)p; p += (size_t)EXP * DMODEL * DMODEL * 2;
  __bf16* hbuf = (__bf16*)p; p += (size_t)TT * DMODEL * 2;
  __bf16* ybuf = (__bf16*)p; p += (size_t)TT * DMODEL * 2;
  int*   idxb   = (int*)p;   p += (size_t)TT * 4;
  float* scoreb = (float*)p; p += (size_t)TT * 4;
  int*   rowlist = (int*)p;  p += (size_t)EXP * CAP * 4;
  int*   cntb    = (int*)p;  p += 64;
  int*   offb    = (int*)p;  p += 64;

  convw_kernel<<<dim3(8192), dim3(256), 0, stream>>>(W1, W2, W1bt, W2bt);
  gate_kernel<<<dim3(4096), dim3(256), 0, stream>>>(moe, gw, gb, rw, rb, idxb, scoreb, Xb);
  scan_kernel<<<dim3(1), dim3(1024), 0, stream>>>(idxb, scoreb, rowlist, cntb, offb);
  moe_gemm<<<dim3(256, 4), dim3(1024), 0, stream>>>(Xb, W1bt, b1, hbuf, rowlist, cntb, offb, 0);
  moe_gemm<<<dim3(256, 4), dim3(1024), 0, stream>>>(hbuf, W2bt, b2, ybuf, rowlist, cntb, offb, 1);
  combine_kernel<<<dim3(16384), dim3(256), 0, stream>>>(ybuf, scoreb, out);
}

// Round 7
// 400.256 us; speedup vs baseline: 1.1152x; 1.1152x over previous
//
#include <hip/hip_runtime.h>
#include <hip/hip_bf16.h>
#include <stdint.h>

#define N_TOK 16384
#define DMODEL 1024
#define EXP 16
#define CAP 4096
#define TT 32768          // N_TOK * K (K=2)

typedef __bf16 bf16x8 __attribute__((ext_vector_type(8)));
typedef __bf16 bf16x4 __attribute__((ext_vector_type(4)));
typedef float  f32x4  __attribute__((ext_vector_type(4)));

__device__ __forceinline__ void gl_lds16(const void* g, void* s) {
  __builtin_amdgcn_global_load_lds(
      (__attribute__((address_space(1))) void*)(void*)g,
      (__attribute__((address_space(3))) void*)s, 16, 0, 0);
}

__device__ __forceinline__ float bfbits2f(unsigned short u) {
  return __uint_as_float(((unsigned)u) << 16);
}

#define FENCE asm volatile("" ::: "memory")
#define BAR() do { FENCE; __builtin_amdgcn_s_barrier(); FENCE; } while (0)

// ------- merged prep: blocks [0,8192) = W transpose+bf16; [8192,12288) = gate -------
__global__ __launch_bounds__(256) void prep_kernel(const float* __restrict__ W1,
                                                   const float* __restrict__ W2,
                                                   __bf16* __restrict__ W1bt,
                                                   __bf16* __restrict__ W2bt,
                                                   const float* __restrict__ x,
                                                   const float* __restrict__ gw,
                                                   const float* __restrict__ gb,
                                                   const float* __restrict__ rw,
                                                   const float* __restrict__ rb,
                                                   int* __restrict__ idxo,
                                                   float* __restrict__ sco,
                                                   __bf16* __restrict__ Xb) {
  __shared__ char smem[36864];
  int bid = blockIdx.x;
  int tid = threadIdx.x;
  if (bid < 8192) {
    // ---------------- convw ----------------
    float (*tile)[65] = (float(*)[65])smem;
    int tx = bid & 15;
    int ty = (bid >> 4) & 15;
    int e  = (bid >> 8) & 15;
    int which = (bid >> 12) & 1;
    const float* src = (which ? W2 : W1) + (size_t)e * DMODEL * DMODEL;
    __bf16*      dst = (which ? W2bt : W1bt) + (size_t)e * DMODEL * DMODEL;
    int r = tid >> 2;
    int cs = (tid & 3) * 16;
    int r0 = ty * 64, c0 = tx * 64;
    #pragma unroll
    for (int i = 0; i < 16; i += 4) {
      float4 v = *(const float4*)(src + (size_t)(r0 + r) * DMODEL + c0 + cs + i);
      tile[r][cs + i + 0] = v.x; tile[r][cs + i + 1] = v.y;
      tile[r][cs + i + 2] = v.z; tile[r][cs + i + 3] = v.w;
    }
    __syncthreads();
    bf16x8 o1, o2;
    #pragma unroll
    for (int i = 0; i < 8; i++) o1[i] = (__bf16)tile[cs + i][r];
    #pragma unroll
    for (int i = 0; i < 8; i++) o2[i] = (__bf16)tile[cs + 8 + i][r];
    *(bf16x8*)(dst + (size_t)(c0 + r) * DMODEL + r0 + cs)     = o1;
    *(bf16x8*)(dst + (size_t)(c0 + r) * DMODEL + r0 + cs + 8) = o2;
  } else {
    // ---------------- gate (fused X->bf16) ----------------
    float* gws = (float*)smem;                 // 512*17 dwords
    float* rws = (float*)(smem + 34816);       // 512 dwords
    int g = bid - 8192;
    int w = tid >> 6, lane = tid & 63;
    int n = g * 4 + w;
    const float* xr = x + (size_t)n * DMODEL;
    __bf16* xbr = Xb + (size_t)n * DMODEL;

    float acc[17];
    #pragma unroll
    for (int j = 0; j < 17; j++) acc[j] = 0.f;

    for (int c = 0; c < 2; c++) {
      int c0 = c * 512;
      __syncthreads();
      for (int i = tid; i < 512 * 16; i += 256)
        gws[(i >> 4) * 17 + (i & 15)] = gw[c0 * 16 + i];
      for (int i = tid; i < 512; i += 256)
        rws[i] = rw[c0 + i];
      __syncthreads();

      float xv[8];
      #pragma unroll
      for (int u = 0; u < 8; u++) xv[u] = xr[c0 + u * 64 + lane];
      #pragma unroll
      for (int u = 0; u < 8; u++) xbr[c0 + u * 64 + lane] = (__bf16)xv[u];
      #pragma unroll
      for (int u = 0; u < 8; u++) {
        int dl = u * 64 + lane;
        const float* gp = &gws[dl * 17];
        #pragma unroll
        for (int j = 0; j < 16; j++) acc[j] += xv[u] * gp[j];
        acc[16] += xv[u] * rws[dl];
      }
    }

    #pragma unroll
    for (int o = 1; o < 64; o <<= 1) {
      #pragma unroll
      for (int j = 0; j < 17; j++) acc[j] += __shfl_xor(acc[j], o);
    }
    if (lane == 0) {
      float rv = acc[16] + rb[0];
      bool g1 = rv > 0.f;
      float c[8];
      #pragma unroll
      for (int j = 0; j < 8; j++)
        c[j] = (g1 ? acc[j] + gb[j] : acc[8 + j] + gb[8 + j]);
      int i1 = 0; float v1 = c[0];
      #pragma unroll
      for (int j = 1; j < 8; j++) { if (c[j] > v1) { v1 = c[j]; i1 = j; } }
      int i2 = -1; float v2 = -3.4e38f;
      #pragma unroll
      for (int j = 0; j < 8; j++) { if (j != i1 && c[j] > v2) { v2 = c[j]; i2 = j; } }
      float e2 = expf(v2 - v1);
      float den = 1.f + e2;
      int base = g1 ? 0 : 8;
      idxo[2 * n] = base + i1; idxo[2 * n + 1] = base + i2;
      sco[2 * n] = 1.f / den;  sco[2 * n + 1] = e2 / den;
    }
  }
}

// ------------- scan: t-ordered per-expert ranks, rowlists, offsets -------------
__global__ __launch_bounds__(1024) void scan_kernel(const int* __restrict__ idx,
                                                    float* __restrict__ sco,
                                                    int* __restrict__ rowlist,
                                                    int* __restrict__ cnt,
                                                    int* __restrict__ off) {
  __shared__ int hist[16 * 1024];   // 64 KB
  int tid = threadIdx.x;
  #pragma unroll
  for (int e = 0; e < 16; e++) hist[e * 1024 + tid] = 0;
  __syncthreads();
  int base = tid * 32;
  for (int i = 0; i < 32; i++) {
    int e = idx[base + i];
    hist[e * 1024 + tid]++;
  }
  __syncthreads();
  int w = tid >> 6, lane = tid & 63;
  {
    int e = w;  // 16 waves == 16 experts
    int running = 0;
    for (int cch = 0; cch < 16; cch++) {
      int v = hist[e * 1024 + cch * 64 + lane];
      int orig = v;
      #pragma unroll
      for (int o = 1; o < 64; o <<= 1) {
        int nv = __shfl_up(v, o);
        if (lane >= o) v += nv;
      }
      hist[e * 1024 + cch * 64 + lane] = running + v - orig;  // exclusive base
      running += __shfl(v, 63);
    }
    if (lane == 0) cnt[e] = running;   // raw count
  }
  __syncthreads();
  if (tid == 0) {
    int o = 0;
    for (int e = 0; e < 16; e++) {
      int c = cnt[e]; if (c > CAP) c = CAP;
      off[e] = o; cnt[e] = c; o += c;
    }
  }
  __syncthreads();
  for (int i = 0; i < 32; i++) {
    int t = base + i;
    int e = idx[t];
    int r = hist[e * 1024 + tid]++;
    if (r < CAP) rowlist[e * CAP + r] = t;
    else sco[t] = 0.f;   // dropped slot contributes zero
  }
}

// ------- grouped GEMM: 128x128x64, 4 waves, 64KB dbuf -> 2 blocks/CU -------
// Schedule per K-tile t (buf b = t&1), 2 barriers:
//  Ph1: 16 ds_reads (A 8, B 8); lgkmcnt(0)+sched_barrier; MFMA acc[*][0-1]; BAR
//  Ph2: stage A(t+2)+B(t+2) -> buf b (safe: all reads of b completed pre-BAR);
//       MFMA acc[*][2-3]; vmcnt(8) [tile t+1 landed]; BAR
#define GBM 128
#define GBN 128
#define GBK 64
#define NKT (DMODEL / GBK)   // 16 K-steps

__global__ __launch_bounds__(256, 2) void moe_gemm(const __bf16* __restrict__ A,
                                                   const __bf16* __restrict__ Bt,
                                                   const float* __restrict__ bias,
                                                   __bf16* __restrict__ out,
                                                   const int* __restrict__ rowlist,
                                                   const int* __restrict__ cnt,
                                                   const int* __restrict__ off,
                                                   int mode) {
  __shared__ char lds[65536];   // A: 2x16KB, B: 2x16KB
  int bx = blockIdx.x;
  // 512 x-blocks = 16 experts x 32 M-tiles; XCD-chunked bijective swizzle (512%8==0)
  int em = (bx & 7) * 64 + (bx >> 3);
  int e  = em >> 5;
  int m0 = (em & 31) * GBM;
  int ce = cnt[e];
  if (m0 >= ce) return;
  int n0 = blockIdx.y * GBN;
  int oe = off[e];
  int tid = threadIdx.x;

  // staging source pointers: 4 granules each for A and B (16B, pre-swizzled)
  const __bf16* aP[4];
  const __bf16* bP[4];
  #pragma unroll
  for (int j = 0; j < 4; j++) {
    int c = j * 256 + tid;
    int srow = c >> 3;                  // 0..127
    int gsrc = (c & 7) ^ (srow & 7);    // pre-swizzled source granule
    int rr = m0 + srow; if (rr > ce - 1) rr = ce - 1;
    size_t arow;
    if (mode == 0) arow = (size_t)(rowlist[e * CAP + rr] >> 1);  // token id
    else           arow = (size_t)(oe + rr);                     // h row
    aP[j] = A + arow * DMODEL + gsrc * 8;
    bP[j] = Bt + (size_t)e * DMODEL * DMODEL + (size_t)(n0 + srow) * DMODEL + gsrc * 8;
  }

  int w = tid >> 6, lane = tid & 63;
  int wr = (w >> 1) * 64;     // wave M-offset
  int wc = (w & 1) * 64;      // wave N-offset
  int fr = lane & 15, fg = lane >> 4;

  int aRd = wr * 128 + fr * 128;
  int bRd = 32768 + wc * 128 + fr * 128;
  int gk0 = ((fg)     ^ (fr & 7)) * 16;
  int gk1 = ((4 | fg) ^ (fr & 7)) * 16;

  f32x4 acc[4][4];
  #pragma unroll
  for (int mi = 0; mi < 4; mi++)
    #pragma unroll
    for (int ni = 0; ni < 4; ni++)
      #pragma unroll
      for (int l = 0; l < 4; l++) acc[mi][ni][l] = 0.f;

  auto stA = [&](int s) {
    char* dst = lds + (s & 1) * 16384;
    #pragma unroll
    for (int j = 0; j < 4; j++)
      gl_lds16(aP[j] + s * 64, dst + (size_t)(j * 256 + tid) * 16);
  };
  auto stB = [&](int s) {
    char* dst = lds + 32768 + (s & 1) * 16384;
    #pragma unroll
    for (int j = 0; j < 4; j++)
      gl_lds16(bP[j] + s * 64, dst + (size_t)(j * 256 + tid) * 16);
  };

  // prologue: tiles 0 and 1 staged; wait tile0 (newest 8 = tile1 in flight)
  stA(0); stB(0); stA(1); stB(1);
  asm volatile("s_waitcnt vmcnt(8)" ::: "memory");
  BAR();

  bf16x8 afA[4][2], bq0[2][2], bq1[2][2];
  for (int t = 0; t < NKT; ++t) {
    const char* Ab = lds + (t & 1) * 16384 + aRd;
    const char* Bb = lds + (t & 1) * 16384 + bRd;

    // ---- Ph1: all 16 fragment reads, then MFMA half 1 ----
    #pragma unroll
    for (int mi = 0; mi < 4; mi++) {
      afA[mi][0] = *(const bf16x8*)(Ab + mi * 2048 + gk0);
      afA[mi][1] = *(const bf16x8*)(Ab + mi * 2048 + gk1);
    }
    #pragma unroll
    for (int ni = 0; ni < 2; ni++) {
      bq0[ni][0] = *(const bf16x8*)(Bb + ni * 2048 + gk0);
      bq0[ni][1] = *(const bf16x8*)(Bb + ni * 2048 + gk1);
      bq1[ni][0] = *(const bf16x8*)(Bb + (2 + ni) * 2048 + gk0);
      bq1[ni][1] = *(const bf16x8*)(Bb + (2 + ni) * 2048 + gk1);
    }
    asm volatile("s_waitcnt lgkmcnt(0)" ::: "memory");
    __builtin_amdgcn_sched_barrier(0);
    __builtin_amdgcn_s_setprio(1);
    #pragma unroll
    for (int kk = 0; kk < 2; kk++)
      #pragma unroll
      for (int mi = 0; mi < 4; mi++)
        #pragma unroll
        for (int ni = 0; ni < 2; ni++)
          acc[mi][ni] = __builtin_amdgcn_mfma_f32_16x16x32_bf16(afA[mi][kk], bq0[ni][kk], acc[mi][ni], 0, 0, 0);
    __builtin_amdgcn_s_setprio(0);
    BAR();   // all waves' reads of buf (t&1) complete before this point

    // ---- Ph2: stage tile t+2 into buf (t&1); MFMA half 2 ----
    if (t <= NKT - 3) { stA(t + 2); stB(t + 2); }
    __builtin_amdgcn_s_setprio(1);
    #pragma unroll
    for (int kk = 0; kk < 2; kk++)
      #pragma unroll
      for (int mi = 0; mi < 4; mi++)
        #pragma unroll
        for (int ni = 0; ni < 2; ni++)
          acc[mi][2 + ni] = __builtin_amdgcn_mfma_f32_16x16x32_bf16(afA[mi][kk], bq1[ni][kk], acc[mi][2 + ni], 0, 0, 0);
    __builtin_amdgcn_s_setprio(0);
    if (t <= NKT - 3)      asm volatile("s_waitcnt vmcnt(8)" ::: "memory");
    else if (t == NKT - 2) asm volatile("s_waitcnt vmcnt(0)" ::: "memory");
    BAR();
  }

  float bcol[4];
  #pragma unroll
  for (int ni = 0; ni < 4; ni++)
    bcol[ni] = bias[(size_t)e * DMODEL + n0 + wc + ni * 16 + fr];
  #pragma unroll
  for (int mi = 0; mi < 4; mi++) {
    #pragma unroll
    for (int r = 0; r < 4; r++) {
      int grow = m0 + wr + mi * 16 + fg * 4 + r;
      if (grow >= ce) continue;
      size_t orow = (mode == 0) ? (size_t)(oe + grow)
                                : (size_t)rowlist[e * CAP + grow];
      __bf16* op = out + orow * DMODEL + n0 + wc + fr;
      #pragma unroll
      for (int ni = 0; ni < 4; ni++) {
        float v = acc[mi][ni][r] + bcol[ni];
        if (mode == 0) v = fmaxf(v, 0.f);
        op[ni * 16] = (__bf16)v;
      }
    }
  }
}

// ---------------- combine: out[n] = s0*y[2n] + s1*y[2n+1] ----------------
__global__ __launch_bounds__(256) void combine_kernel(const __bf16* __restrict__ y,
                                                      const float* __restrict__ sco,
                                                      float* __restrict__ out) {
  int n = blockIdx.x;
  int d = threadIdx.x * 4;
  float s0 = sco[2 * n], s1 = sco[2 * n + 1];
  ushort4 a = *(const ushort4*)((const unsigned short*)(y + (size_t)(2 * n) * DMODEL + d));
  ushort4 b = *(const ushort4*)((const unsigned short*)(y + (size_t)(2 * n + 1) * DMODEL + d));
  float4 o;
  o.x = s0 * bfbits2f(a.x) + s1 * bfbits2f(b.x);
  o.y = s0 * bfbits2f(a.y) + s1 * bfbits2f(b.y);
  o.z = s0 * bfbits2f(a.z) + s1 * bfbits2f(b.z);
  o.w = s0 * bfbits2f(a.w) + s1 * bfbits2f(b.w);
  *(float4*)(out + (size_t)n * DMODEL + d) = o;
}

extern "C" void kernel_launch(void* const* d_in, const int* in_sizes, int n_in,
                              void* d_out, int out_size, void* d_ws, size_t ws_size,
                              hipStream_t stream) {
  const float* moe = (const float*)d_in[0];
  const float* gw  = (const float*)d_in[1];
  const float* gb  = (const float*)d_in[2];
  const float* rw  = (const float*)d_in[3];
  const float* rb  = (const float*)d_in[4];
  const float* W1  = (const float*)d_in[5];
  const float* b1  = (const float*)d_in[6];
  const float* W2  = (const float*)d_in[7];
  const float* b2  = (const float*)d_in[8];
  float* out = (float*)d_out;

  char* p = (char*)d_ws;
  __bf16* Xb   = (__bf16*)p; p += (size_t)N_TOK * DMODEL * 2;
  __bf16* W1bt = (__bf16*)p; p += (size_t)EXP * DMODEL * DMODEL * 2;
  __bf16* W2bt = (__bf16*)p; p += (size_t)EXP * DMODEL * DMODEL * 2;
  __bf16* hbuf = (__bf16*)p; p += (size_t)TT * DMODEL * 2;
  __bf16* ybuf = (__bf16*)p; p += (size_t)TT * DMODEL * 2;
  int*   idxb   = (int*)p;   p += (size_t)TT * 4;
  float* scoreb = (float*)p; p += (size_t)TT * 4;
  int*   rowlist = (int*)p;  p += (size_t)EXP * CAP * 4;
  int*   cntb    = (int*)p;  p += 64;
  int*   offb    = (int*)p;  p += 64;

  prep_kernel<<<dim3(12288), dim3(256), 0, stream>>>(W1, W2, W1bt, W2bt,
                                                     moe, gw, gb, rw, rb,
                                                     idxb, scoreb, Xb);
  scan_kernel<<<dim3(1), dim3(1024), 0, stream>>>(idxb, scoreb, rowlist, cntb, offb);
  moe_gemm<<<dim3(512, 8), dim3(256), 0, stream>>>(Xb, W1bt, b1, hbuf, rowlist, cntb, offb, 0);
  moe_gemm<<<dim3(512, 8), dim3(256), 0, stream>>>(hbuf, W2bt, b2, ybuf, rowlist, cntb, offb, 1);
  combine_kernel<<<dim3(16384), dim3(256), 0, stream>>>(ybuf, scoreb, out);
}

// Round 8
// 391.818 us; speedup vs baseline: 1.1392x; 1.0215x over previous
//
#include <hip/hip_runtime.h>
#include <hip/hip_bf16.h>
#include <stdint.h>

#define N_TOK 16384
#define DMODEL 1024
#define EXP 16
#define CAP 4096
#define TT 32768          // N_TOK * K (K=2)

typedef __bf16 bf16x8 __attribute__((ext_vector_type(8)));
typedef __bf16 bf16x4 __attribute__((ext_vector_type(4)));
typedef float  f32x4  __attribute__((ext_vector_type(4)));

__device__ __forceinline__ void gl_lds16(const void* g, void* s) {
  __builtin_amdgcn_global_load_lds(
      (__attribute__((address_space(1))) void*)(void*)g,
      (__attribute__((address_space(3))) void*)s, 16, 0, 0);
}

__device__ __forceinline__ float bfbits2f(unsigned short u) {
  return __uint_as_float(((unsigned)u) << 16);
}

#define FENCE asm volatile("" ::: "memory")
#define BAR() do { FENCE; __builtin_amdgcn_s_barrier(); FENCE; } while (0)

// ------- merged prep, interleaved: bid%3==2 -> gate, else -> convw -------
// LDS 21504 B -> 7 blocks/CU. gw staged in 4 chunks of 256 rows, stride 20
// dwords (start banks (20*lane)%32 cover all 32 banks per 8 lanes -> b128
// conflict-free at the inherent 8-slot minimum).
__global__ __launch_bounds__(256) void prep_kernel(const float* __restrict__ W1,
                                                   const float* __restrict__ W2,
                                                   __bf16* __restrict__ W1bt,
                                                   __bf16* __restrict__ W2bt,
                                                   const float* __restrict__ x,
                                                   const float* __restrict__ gw,
                                                   const float* __restrict__ gb,
                                                   const float* __restrict__ rw,
                                                   const float* __restrict__ rb,
                                                   int* __restrict__ idxo,
                                                   float* __restrict__ sco,
                                                   __bf16* __restrict__ Xb) {
  __shared__ char smem[21504];
  int bid = blockIdx.x;
  int tid = threadIdx.x;
  if (bid % 3 != 2) {
    // ---------------- convw ----------------
    int cb = bid - (bid + 1) / 3;          // 0..8191 bijective
    float (*tile)[65] = (float(*)[65])smem;
    int tx = cb & 15;
    int ty = (cb >> 4) & 15;
    int e  = (cb >> 8) & 15;
    int which = (cb >> 12) & 1;
    const float* src = (which ? W2 : W1) + (size_t)e * DMODEL * DMODEL;
    __bf16*      dst = (which ? W2bt : W1bt) + (size_t)e * DMODEL * DMODEL;
    int r = tid >> 2;
    int cs = (tid & 3) * 16;
    int r0 = ty * 64, c0 = tx * 64;
    #pragma unroll
    for (int i = 0; i < 16; i += 4) {
      float4 v = *(const float4*)(src + (size_t)(r0 + r) * DMODEL + c0 + cs + i);
      tile[r][cs + i + 0] = v.x; tile[r][cs + i + 1] = v.y;
      tile[r][cs + i + 2] = v.z; tile[r][cs + i + 3] = v.w;
    }
    __syncthreads();
    bf16x8 o1, o2;
    #pragma unroll
    for (int i = 0; i < 8; i++) o1[i] = (__bf16)tile[cs + i][r];
    #pragma unroll
    for (int i = 0; i < 8; i++) o2[i] = (__bf16)tile[cs + 8 + i][r];
    *(bf16x8*)(dst + (size_t)(c0 + r) * DMODEL + r0 + cs)     = o1;
    *(bf16x8*)(dst + (size_t)(c0 + r) * DMODEL + r0 + cs + 8) = o2;
  } else {
    // ---------------- gate (fused X->bf16) ----------------
    float* gws = (float*)smem;               // 256 rows * 20 dwords = 20480 B
    float* rws = (float*)(smem + 20480);     // 256 dwords = 1024 B
    int g = bid / 3;                         // 0..4095
    int w = tid >> 6, lane = tid & 63;
    int n = g * 4 + w;
    const float* xr = x + (size_t)n * DMODEL;
    __bf16* xbr = Xb + (size_t)n * DMODEL;

    float acc[17];
    #pragma unroll
    for (int j = 0; j < 17; j++) acc[j] = 0.f;

    for (int c = 0; c < 4; c++) {
      int c0 = c * 256;
      __syncthreads();   // previous chunk fully consumed
      #pragma unroll
      for (int q = tid, it = 0; it < 4; q += 256, it++) {
        float4 v = *(const float4*)(gw + c0 * 16 + q * 4);
        *(float4*)(gws + (q >> 2) * 20 + (q & 3) * 4) = v;
      }
      rws[tid] = rw[c0 + tid];
      __syncthreads();

      #pragma unroll
      for (int u = 0; u < 4; u++) {
        int dl = u * 64 + lane;
        float xv = xr[c0 + dl];
        xbr[c0 + dl] = (__bf16)xv;
        const float* gp = gws + dl * 20;
        float4 g0 = *(const float4*)(gp);
        float4 g1 = *(const float4*)(gp + 4);
        float4 g2 = *(const float4*)(gp + 8);
        float4 g3 = *(const float4*)(gp + 12);
        acc[0]  += xv * g0.x; acc[1]  += xv * g0.y; acc[2]  += xv * g0.z; acc[3]  += xv * g0.w;
        acc[4]  += xv * g1.x; acc[5]  += xv * g1.y; acc[6]  += xv * g1.z; acc[7]  += xv * g1.w;
        acc[8]  += xv * g2.x; acc[9]  += xv * g2.y; acc[10] += xv * g2.z; acc[11] += xv * g2.w;
        acc[12] += xv * g3.x; acc[13] += xv * g3.y; acc[14] += xv * g3.z; acc[15] += xv * g3.w;
        acc[16] += xv * rws[dl];
      }
    }

    #pragma unroll
    for (int o = 1; o < 64; o <<= 1) {
      #pragma unroll
      for (int j = 0; j < 17; j++) acc[j] += __shfl_xor(acc[j], o);
    }
    if (lane == 0) {
      float rv = acc[16] + rb[0];
      bool g1 = rv > 0.f;
      float c[8];
      #pragma unroll
      for (int j = 0; j < 8; j++)
        c[j] = (g1 ? acc[j] + gb[j] : acc[8 + j] + gb[8 + j]);
      int i1 = 0; float v1 = c[0];
      #pragma unroll
      for (int j = 1; j < 8; j++) { if (c[j] > v1) { v1 = c[j]; i1 = j; } }
      int i2 = -1; float v2 = -3.4e38f;
      #pragma unroll
      for (int j = 0; j < 8; j++) { if (j != i1 && c[j] > v2) { v2 = c[j]; i2 = j; } }
      float e2 = expf(v2 - v1);
      float den = 1.f + e2;
      int base = g1 ? 0 : 8;
      idxo[2 * n] = base + i1; idxo[2 * n + 1] = base + i2;
      sco[2 * n] = 1.f / den;  sco[2 * n + 1] = e2 / den;
    }
  }
}

// ------------- scan: t-ordered per-expert ranks, rowlists, offsets -------------
__global__ __launch_bounds__(1024) void scan_kernel(const int* __restrict__ idx,
                                                    float* __restrict__ sco,
                                                    int* __restrict__ rowlist,
                                                    int* __restrict__ cnt,
                                                    int* __restrict__ off) {
  __shared__ int hist[16 * 1024];   // 64 KB
  int tid = threadIdx.x;
  #pragma unroll
  for (int e = 0; e < 16; e++) hist[e * 1024 + tid] = 0;
  __syncthreads();
  int base = tid * 32;
  for (int i = 0; i < 32; i++) {
    int e = idx[base + i];
    hist[e * 1024 + tid]++;
  }
  __syncthreads();
  int w = tid >> 6, lane = tid & 63;
  {
    int e = w;  // 16 waves == 16 experts
    int running = 0;
    for (int cch = 0; cch < 16; cch++) {
      int v = hist[e * 1024 + cch * 64 + lane];
      int orig = v;
      #pragma unroll
      for (int o = 1; o < 64; o <<= 1) {
        int nv = __shfl_up(v, o);
        if (lane >= o) v += nv;
      }
      hist[e * 1024 + cch * 64 + lane] = running + v - orig;  // exclusive base
      running += __shfl(v, 63);
    }
    if (lane == 0) cnt[e] = running;   // raw count
  }
  __syncthreads();
  if (tid == 0) {
    int o = 0;
    for (int e = 0; e < 16; e++) {
      int c = cnt[e]; if (c > CAP) c = CAP;
      off[e] = o; cnt[e] = c; o += c;
    }
  }
  __syncthreads();
  for (int i = 0; i < 32; i++) {
    int t = base + i;
    int e = idx[t];
    int r = hist[e * 1024 + tid]++;
    if (r < CAP) rowlist[e * CAP + r] = t;
    else sco[t] = 0.f;   // dropped slot contributes zero
  }
}

// ------- grouped GEMM: 128x128x64, 4 waves, 64KB dbuf -> 2 blocks/CU -------
#define GBM 128
#define GBN 128
#define GBK 64
#define NKT (DMODEL / GBK)   // 16 K-steps

__global__ __launch_bounds__(256, 2) void moe_gemm(const __bf16* __restrict__ A,
                                                   const __bf16* __restrict__ Bt,
                                                   const float* __restrict__ bias,
                                                   __bf16* __restrict__ out,
                                                   const int* __restrict__ rowlist,
                                                   const int* __restrict__ cnt,
                                                   const int* __restrict__ off,
                                                   int mode) {
  __shared__ char lds[65536];   // A: 2x16KB, B: 2x16KB
  int bx = blockIdx.x;
  // 512 x-blocks = 16 experts x 32 M-tiles; XCD-chunked bijective swizzle (512%8==0)
  int em = (bx & 7) * 64 + (bx >> 3);
  int e  = em >> 5;
  int m0 = (em & 31) * GBM;
  int ce = cnt[e];
  if (m0 >= ce) return;
  int n0 = blockIdx.y * GBN;
  int oe = off[e];
  int tid = threadIdx.x;

  // staging source pointers: 4 granules each for A and B (16B, pre-swizzled)
  const __bf16* aP[4];
  const __bf16* bP[4];
  #pragma unroll
  for (int j = 0; j < 4; j++) {
    int c = j * 256 + tid;
    int srow = c >> 3;                  // 0..127
    int gsrc = (c & 7) ^ (srow & 7);    // pre-swizzled source granule
    int rr = m0 + srow; if (rr > ce - 1) rr = ce - 1;
    size_t arow;
    if (mode == 0) arow = (size_t)(rowlist[e * CAP + rr] >> 1);  // token id
    else           arow = (size_t)(oe + rr);                     // h row
    aP[j] = A + arow * DMODEL + gsrc * 8;
    bP[j] = Bt + (size_t)e * DMODEL * DMODEL + (size_t)(n0 + srow) * DMODEL + gsrc * 8;
  }

  int w = tid >> 6, lane = tid & 63;
  int wr = (w >> 1) * 64;     // wave M-offset
  int wc = (w & 1) * 64;      // wave N-offset
  int fr = lane & 15, fg = lane >> 4;

  int aRd = wr * 128 + fr * 128;
  int bRd = 32768 + wc * 128 + fr * 128;
  int gk0 = ((fg)     ^ (fr & 7)) * 16;
  int gk1 = ((4 | fg) ^ (fr & 7)) * 16;

  f32x4 acc[4][4];
  #pragma unroll
  for (int mi = 0; mi < 4; mi++)
    #pragma unroll
    for (int ni = 0; ni < 4; ni++)
      #pragma unroll
      for (int l = 0; l < 4; l++) acc[mi][ni][l] = 0.f;

  auto stA = [&](int s) {
    char* dst = lds + (s & 1) * 16384;
    #pragma unroll
    for (int j = 0; j < 4; j++)
      gl_lds16(aP[j] + s * 64, dst + (size_t)(j * 256 + tid) * 16);
  };
  auto stB = [&](int s) {
    char* dst = lds + 32768 + (s & 1) * 16384;
    #pragma unroll
    for (int j = 0; j < 4; j++)
      gl_lds16(bP[j] + s * 64, dst + (size_t)(j * 256 + tid) * 16);
  };

  // prologue: tiles 0 and 1 staged; wait tile0 (newest 8 = tile1 in flight)
  stA(0); stB(0); stA(1); stB(1);
  asm volatile("s_waitcnt vmcnt(8)" ::: "memory");
  BAR();

  bf16x8 afA[4][2], bq0[2][2], bq1[2][2];
  for (int t = 0; t < NKT; ++t) {
    const char* Ab = lds + (t & 1) * 16384 + aRd;
    const char* Bb = lds + (t & 1) * 16384 + bRd;

    // ---- Ph1: all 16 fragment reads, then MFMA half 1 ----
    #pragma unroll
    for (int mi = 0; mi < 4; mi++) {
      afA[mi][0] = *(const bf16x8*)(Ab + mi * 2048 + gk0);
      afA[mi][1] = *(const bf16x8*)(Ab + mi * 2048 + gk1);
    }
    #pragma unroll
    for (int ni = 0; ni < 2; ni++) {
      bq0[ni][0] = *(const bf16x8*)(Bb + ni * 2048 + gk0);
      bq0[ni][1] = *(const bf16x8*)(Bb + ni * 2048 + gk1);
      bq1[ni][0] = *(const bf16x8*)(Bb + (2 + ni) * 2048 + gk0);
      bq1[ni][1] = *(const bf16x8*)(Bb + (2 + ni) * 2048 + gk1);
    }
    asm volatile("s_waitcnt lgkmcnt(0)" ::: "memory");
    __builtin_amdgcn_sched_barrier(0);
    __builtin_amdgcn_s_setprio(1);
    #pragma unroll
    for (int kk = 0; kk < 2; kk++)
      #pragma unroll
      for (int mi = 0; mi < 4; mi++)
        #pragma unroll
        for (int ni = 0; ni < 2; ni++)
          acc[mi][ni] = __builtin_amdgcn_mfma_f32_16x16x32_bf16(afA[mi][kk], bq0[ni][kk], acc[mi][ni], 0, 0, 0);
    __builtin_amdgcn_s_setprio(0);
    BAR();   // all waves' reads of buf (t&1) complete before this point

    // ---- Ph2: stage tile t+2 into buf (t&1); MFMA half 2 ----
    if (t <= NKT - 3) { stA(t + 2); stB(t + 2); }
    __builtin_amdgcn_s_setprio(1);
    #pragma unroll
    for (int kk = 0; kk < 2; kk++)
      #pragma unroll
      for (int mi = 0; mi < 4; mi++)
        #pragma unroll
        for (int ni = 0; ni < 2; ni++)
          acc[mi][2 + ni] = __builtin_amdgcn_mfma_f32_16x16x32_bf16(afA[mi][kk], bq1[ni][kk], acc[mi][2 + ni], 0, 0, 0);
    __builtin_amdgcn_s_setprio(0);
    if (t <= NKT - 3)      asm volatile("s_waitcnt vmcnt(8)" ::: "memory");
    else if (t == NKT - 2) asm volatile("s_waitcnt vmcnt(0)" ::: "memory");
    BAR();
  }

  float bcol[4];
  #pragma unroll
  for (int ni = 0; ni < 4; ni++)
    bcol[ni] = bias[(size_t)e * DMODEL + n0 + wc + ni * 16 + fr];
  #pragma unroll
  for (int mi = 0; mi < 4; mi++) {
    #pragma unroll
    for (int r = 0; r < 4; r++) {
      int grow = m0 + wr + mi * 16 + fg * 4 + r;
      if (grow >= ce) continue;
      size_t orow = (mode == 0) ? (size_t)(oe + grow)
                                : (size_t)rowlist[e * CAP + grow];
      __bf16* op = out + orow * DMODEL + n0 + wc + fr;
      #pragma unroll
      for (int ni = 0; ni < 4; ni++) {
        float v = acc[mi][ni][r] + bcol[ni];
        if (mode == 0) v = fmaxf(v, 0.f);
        op[ni * 16] = (__bf16)v;
      }
    }
  }
}

// ---------------- combine: out[n] = s0*y[2n] + s1*y[2n+1] ----------------
__global__ __launch_bounds__(256) void combine_kernel(const __bf16* __restrict__ y,
                                                      const float* __restrict__ sco,
                                                      float* __restrict__ out) {
  int n = blockIdx.x;
  int d = threadIdx.x * 4;
  float s0 = sco[2 * n], s1 = sco[2 * n + 1];
  ushort4 a = *(const ushort4*)((const unsigned short*)(y + (size_t)(2 * n) * DMODEL + d));
  ushort4 b = *(const ushort4*)((const unsigned short*)(y + (size_t)(2 * n + 1) * DMODEL + d));
  float4 o;
  o.x = s0 * bfbits2f(a.x) + s1 * bfbits2f(b.x);
  o.y = s0 * bfbits2f(a.y) + s1 * bfbits2f(b.y);
  o.z = s0 * bfbits2f(a.z) + s1 * bfbits2f(b.z);
  o.w = s0 * bfbits2f(a.w) + s1 * bfbits2f(b.w);
  *(float4*)(out + (size_t)n * DMODEL + d) = o;
}

extern "C" void kernel_launch(void* const* d_in, const int* in_sizes, int n_in,
                              void* d_out, int out_size, void* d_ws, size_t ws_size,
                              hipStream_t stream) {
  const float* moe = (const float*)d_in[0];
  const float* gw  = (const float*)d_in[1];
  const float* gb  = (const float*)d_in[2];
  const float* rw  = (const float*)d_in[3];
  const float* rb  = (const float*)d_in[4];
  const float* W1  = (const float*)d_in[5];
  const float* b1  = (const float*)d_in[6];
  const float* W2  = (const float*)d_in[7];
  const float* b2  = (const float*)d_in[8];
  float* out = (float*)d_out;

  char* p = (char*)d_ws;
  __bf16* Xb   = (__bf16*)p; p += (size_t)N_TOK * DMODEL * 2;
  __bf16* W1bt = (__bf16*)p; p += (size_t)EXP * DMODEL * DMODEL * 2;
  __bf16* W2bt = (__bf16*)p; p += (size_t)EXP * DMODEL * DMODEL * 2;
  __bf16* hbuf = (__bf16*)p; p += (size_t)TT * DMODEL * 2;
  __bf16* ybuf = (__bf16*)p; p += (size_t)TT * DMODEL * 2;
  int*   idxb   = (int*)p;   p += (size_t)TT * 4;
  float* scoreb = (float*)p; p += (size_t)TT * 4;
  int*   rowlist = (int*)p;  p += (size_t)EXP * CAP * 4;
  int*   cntb    = (int*)p;  p += 64;
  int*   offb    = (int*)p;  p += 64;

  prep_kernel<<<dim3(12288), dim3(256), 0, stream>>>(W1, W2, W1bt, W2bt,
                                                     moe, gw, gb, rw, rb,
                                                     idxb, scoreb, Xb);
  scan_kernel<<<dim3(1), dim3(1024), 0, stream>>>(idxb, scoreb, rowlist, cntb, offb);
  moe_gemm<<<dim3(512, 8), dim3(256), 0, stream>>>(Xb, W1bt, b1, hbuf, rowlist, cntb, offb, 0);
  moe_gemm<<<dim3(512, 8), dim3(256), 0, stream>>>(hbuf, W2bt, b2, ybuf, rowlist, cntb, offb, 1);
  combine_kernel<<<dim3(16384), dim3(256), 0, stream>>>(ybuf, scoreb, out);
}

// Round 9
// 367.326 us; speedup vs baseline: 1.2152x; 1.0667x over previous
//
#include <hip/hip_runtime.h>
#include <hip/hip_bf16.h>
#include <stdint.h>

#define N_TOK 16384
#define DMODEL 1024
#define EXP 16
#define CAP 4096
#define TT 32768          // N_TOK * K (K=2)

typedef __bf16 bf16x8 __attribute__((ext_vector_type(8)));
typedef __bf16 bf16x4 __attribute__((ext_vector_type(4)));
typedef float  f32x4  __attribute__((ext_vector_type(4)));

__device__ __forceinline__ void gl_lds16(const void* g, void* s) {
  __builtin_amdgcn_global_load_lds(
      (__attribute__((address_space(1))) void*)(void*)g,
      (__attribute__((address_space(3))) void*)s, 16, 0, 0);
}

__device__ __forceinline__ float bfbits2f(unsigned short u) {
  return __uint_as_float(((unsigned)u) << 16);
}

#define FENCE asm volatile("" ::: "memory")
#define BAR() do { FENCE; __builtin_amdgcn_s_barrier(); FENCE; } while (0)

// ------- merged prep, interleaved: bid%9==8 -> gate (1024), else convw (8192) -------
// gate: 16 tokens/block (4 per wave, register-blocked) -> gw staged 4x fewer
// times and 4x fewer blocks/syncs than R8. Same per-lane fp32 accumulation
// order as R8 (bitwise-identical routing).
__global__ __launch_bounds__(256) void prep_kernel(const float* __restrict__ W1,
                                                   const float* __restrict__ W2,
                                                   __bf16* __restrict__ W1bt,
                                                   __bf16* __restrict__ W2bt,
                                                   const float* __restrict__ x,
                                                   const float* __restrict__ gw,
                                                   const float* __restrict__ gb,
                                                   const float* __restrict__ rw,
                                                   const float* __restrict__ rb,
                                                   int* __restrict__ idxo,
                                                   float* __restrict__ sco,
                                                   __bf16* __restrict__ Xb) {
  __shared__ char smem[21504];
  int bid = blockIdx.x;
  int tid = threadIdx.x;
  if (bid % 9 != 8) {
    // ---------------- convw ----------------
    int cb = bid - (bid + 1) / 9;          // 0..8191 bijective
    float (*tile)[65] = (float(*)[65])smem;
    int tx = cb & 15;
    int ty = (cb >> 4) & 15;
    int e  = (cb >> 8) & 15;
    int which = (cb >> 12) & 1;
    const float* src = (which ? W2 : W1) + (size_t)e * DMODEL * DMODEL;
    __bf16*      dst = (which ? W2bt : W1bt) + (size_t)e * DMODEL * DMODEL;
    int r = tid >> 2;
    int cs = (tid & 3) * 16;
    int r0 = ty * 64, c0 = tx * 64;
    #pragma unroll
    for (int i = 0; i < 16; i += 4) {
      float4 v = *(const float4*)(src + (size_t)(r0 + r) * DMODEL + c0 + cs + i);
      tile[r][cs + i + 0] = v.x; tile[r][cs + i + 1] = v.y;
      tile[r][cs + i + 2] = v.z; tile[r][cs + i + 3] = v.w;
    }
    __syncthreads();
    bf16x8 o1, o2;
    #pragma unroll
    for (int i = 0; i < 8; i++) o1[i] = (__bf16)tile[cs + i][r];
    #pragma unroll
    for (int i = 0; i < 8; i++) o2[i] = (__bf16)tile[cs + 8 + i][r];
    *(bf16x8*)(dst + (size_t)(c0 + r) * DMODEL + r0 + cs)     = o1;
    *(bf16x8*)(dst + (size_t)(c0 + r) * DMODEL + r0 + cs + 8) = o2;
  } else {
    // ---------------- gate: 4 tokens per wave, fused X->bf16 ----------------
    float* gws = (float*)smem;               // 256 rows * 20 dwords = 20480 B
    float* rws = (float*)(smem + 20480);     // 256 dwords = 1024 B
    int g = bid / 9;                         // 0..1023
    int w = tid >> 6, lane = tid & 63;
    int n0t = g * 16 + w * 4;                // first of this wave's 4 tokens
    const float* xr0 = x + (size_t)(n0t + 0) * DMODEL;
    const float* xr1 = x + (size_t)(n0t + 1) * DMODEL;
    const float* xr2 = x + (size_t)(n0t + 2) * DMODEL;
    const float* xr3 = x + (size_t)(n0t + 3) * DMODEL;

    float acc0[17], acc1[17], acc2[17], acc3[17];
    #pragma unroll
    for (int j = 0; j < 17; j++) { acc0[j] = 0.f; acc1[j] = 0.f; acc2[j] = 0.f; acc3[j] = 0.f; }

    for (int c = 0; c < 4; c++) {
      int c0 = c * 256;
      __syncthreads();   // previous chunk fully consumed
      #pragma unroll
      for (int q = tid, it = 0; it < 4; q += 256, it++) {
        float4 v = *(const float4*)(gw + c0 * 16 + q * 4);
        *(float4*)(gws + (q >> 2) * 20 + (q & 3) * 4) = v;
      }
      rws[tid] = rw[c0 + tid];
      __syncthreads();

      #pragma unroll
      for (int dv = 0; dv < 4; dv++) {
        int dl = dv * 64 + lane;
        int d  = c0 + dl;
        float x0 = xr0[d], x1 = xr1[d], x2 = xr2[d], x3 = xr3[d];
        Xb[(size_t)(n0t + 0) * DMODEL + d] = (__bf16)x0;
        Xb[(size_t)(n0t + 1) * DMODEL + d] = (__bf16)x1;
        Xb[(size_t)(n0t + 2) * DMODEL + d] = (__bf16)x2;
        Xb[(size_t)(n0t + 3) * DMODEL + d] = (__bf16)x3;
        const float* gp = gws + dl * 20;
        float4 g0 = *(const float4*)(gp);
        float4 g1 = *(const float4*)(gp + 4);
        float4 g2 = *(const float4*)(gp + 8);
        float4 g3 = *(const float4*)(gp + 12);
        float rv = rws[dl];
        float gj[16] = {g0.x, g0.y, g0.z, g0.w, g1.x, g1.y, g1.z, g1.w,
                        g2.x, g2.y, g2.z, g2.w, g3.x, g3.y, g3.z, g3.w};
        #pragma unroll
        for (int j = 0; j < 16; j++) {
          acc0[j] += x0 * gj[j]; acc1[j] += x1 * gj[j];
          acc2[j] += x2 * gj[j]; acc3[j] += x3 * gj[j];
        }
        acc0[16] += x0 * rv; acc1[16] += x1 * rv;
        acc2[16] += x2 * rv; acc3[16] += x3 * rv;
      }
    }

    #pragma unroll
    for (int o = 1; o < 64; o <<= 1) {
      #pragma unroll
      for (int j = 0; j < 17; j++) {
        acc0[j] += __shfl_xor(acc0[j], o);
        acc1[j] += __shfl_xor(acc1[j], o);
        acc2[j] += __shfl_xor(acc2[j], o);
        acc3[j] += __shfl_xor(acc3[j], o);
      }
    }
    if (lane == 0) {
      float* accs[4] = {acc0, acc1, acc2, acc3};
      #pragma unroll
      for (int tk = 0; tk < 4; tk++) {
        float* acc = accs[tk];
        int n = n0t + tk;
        float rv = acc[16] + rb[0];
        bool g1f = rv > 0.f;
        float c[8];
        #pragma unroll
        for (int j = 0; j < 8; j++)
          c[j] = (g1f ? acc[j] + gb[j] : acc[8 + j] + gb[8 + j]);
        int i1 = 0; float v1 = c[0];
        #pragma unroll
        for (int j = 1; j < 8; j++) { if (c[j] > v1) { v1 = c[j]; i1 = j; } }
        int i2 = -1; float v2 = -3.4e38f;
        #pragma unroll
        for (int j = 0; j < 8; j++) { if (j != i1 && c[j] > v2) { v2 = c[j]; i2 = j; } }
        float e2 = expf(v2 - v1);
        float den = 1.f + e2;
        int base = g1f ? 0 : 8;
        idxo[2 * n] = base + i1; idxo[2 * n + 1] = base + i2;
        sco[2 * n] = 1.f / den;  sco[2 * n + 1] = e2 / den;
      }
    }
  }
}

// ------------- scan: t-ordered per-expert ranks, rowlists, offsets -------------
__global__ __launch_bounds__(1024) void scan_kernel(const int* __restrict__ idx,
                                                    float* __restrict__ sco,
                                                    int* __restrict__ rowlist,
                                                    int* __restrict__ cnt,
                                                    int* __restrict__ off) {
  __shared__ int hist[16 * 1024];   // 64 KB
  int tid = threadIdx.x;
  #pragma unroll
  for (int e = 0; e < 16; e++) hist[e * 1024 + tid] = 0;
  __syncthreads();
  int base = tid * 32;
  for (int i = 0; i < 32; i++) {
    int e = idx[base + i];
    hist[e * 1024 + tid]++;
  }
  __syncthreads();
  int w = tid >> 6, lane = tid & 63;
  {
    int e = w;  // 16 waves == 16 experts
    int running = 0;
    for (int cch = 0; cch < 16; cch++) {
      int v = hist[e * 1024 + cch * 64 + lane];
      int orig = v;
      #pragma unroll
      for (int o = 1; o < 64; o <<= 1) {
        int nv = __shfl_up(v, o);
        if (lane >= o) v += nv;
      }
      hist[e * 1024 + cch * 64 + lane] = running + v - orig;  // exclusive base
      running += __shfl(v, 63);
    }
    if (lane == 0) cnt[e] = running;   // raw count
  }
  __syncthreads();
  if (tid == 0) {
    int o = 0;
    for (int e = 0; e < 16; e++) {
      int c = cnt[e]; if (c > CAP) c = CAP;
      off[e] = o; cnt[e] = c; o += c;
    }
  }
  __syncthreads();
  for (int i = 0; i < 32; i++) {
    int t = base + i;
    int e = idx[t];
    int r = hist[e * 1024 + tid]++;
    if (r < CAP) rowlist[e * CAP + r] = t;
    else sco[t] = 0.f;   // dropped slot contributes zero
  }
}

// ------- grouped GEMM: 128x128x64, 4 waves, 64KB dbuf -> 2 blocks/CU -------
#define GBM 128
#define GBN 128
#define GBK 64
#define NKT (DMODEL / GBK)   // 16 K-steps

__global__ __launch_bounds__(256, 2) void moe_gemm(const __bf16* __restrict__ A,
                                                   const __bf16* __restrict__ Bt,
                                                   const float* __restrict__ bias,
                                                   __bf16* __restrict__ out,
                                                   const int* __restrict__ rowlist,
                                                   const int* __restrict__ cnt,
                                                   const int* __restrict__ off,
                                                   int mode) {
  __shared__ char lds[65536];   // A: 2x16KB, B: 2x16KB
  int bx = blockIdx.x;
  // 512 x-blocks = 16 experts x 32 M-tiles; XCD-chunked bijective swizzle (512%8==0)
  int em = (bx & 7) * 64 + (bx >> 3);
  int e  = em >> 5;
  int m0 = (em & 31) * GBM;
  int ce = cnt[e];
  if (m0 >= ce) return;
  int n0 = blockIdx.y * GBN;
  int oe = off[e];
  int tid = threadIdx.x;

  // staging source pointers: 4 granules each for A and B (16B, pre-swizzled)
  const __bf16* aP[4];
  const __bf16* bP[4];
  #pragma unroll
  for (int j = 0; j < 4; j++) {
    int c = j * 256 + tid;
    int srow = c >> 3;                  // 0..127
    int gsrc = (c & 7) ^ (srow & 7);    // pre-swizzled source granule
    int rr = m0 + srow; if (rr > ce - 1) rr = ce - 1;
    size_t arow;
    if (mode == 0) arow = (size_t)(rowlist[e * CAP + rr] >> 1);  // token id
    else           arow = (size_t)(oe + rr);                     // h row
    aP[j] = A + arow * DMODEL + gsrc * 8;
    bP[j] = Bt + (size_t)e * DMODEL * DMODEL + (size_t)(n0 + srow) * DMODEL + gsrc * 8;
  }

  int w = tid >> 6, lane = tid & 63;
  int wr = (w >> 1) * 64;     // wave M-offset
  int wc = (w & 1) * 64;      // wave N-offset
  int fr = lane & 15, fg = lane >> 4;

  int aRd = wr * 128 + fr * 128;
  int bRd = 32768 + wc * 128 + fr * 128;
  int gk0 = ((fg)     ^ (fr & 7)) * 16;
  int gk1 = ((4 | fg) ^ (fr & 7)) * 16;

  f32x4 acc[4][4];
  #pragma unroll
  for (int mi = 0; mi < 4; mi++)
    #pragma unroll
    for (int ni = 0; ni < 4; ni++)
      #pragma unroll
      for (int l = 0; l < 4; l++) acc[mi][ni][l] = 0.f;

  auto stA = [&](int s) {
    char* dst = lds + (s & 1) * 16384;
    #pragma unroll
    for (int j = 0; j < 4; j++)
      gl_lds16(aP[j] + s * 64, dst + (size_t)(j * 256 + tid) * 16);
  };
  auto stB = [&](int s) {
    char* dst = lds + 32768 + (s & 1) * 16384;
    #pragma unroll
    for (int j = 0; j < 4; j++)
      gl_lds16(bP[j] + s * 64, dst + (size_t)(j * 256 + tid) * 16);
  };

  // prologue: tiles 0 and 1 staged; wait tile0 (newest 8 = tile1 in flight)
  stA(0); stB(0); stA(1); stB(1);
  asm volatile("s_waitcnt vmcnt(8)" ::: "memory");
  BAR();

  bf16x8 afA[4][2], bq0[2][2], bq1[2][2];
  for (int t = 0; t < NKT; ++t) {
    const char* Ab = lds + (t & 1) * 16384 + aRd;
    const char* Bb = lds + (t & 1) * 16384 + bRd;

    // ---- Ph1: all 16 fragment reads, then MFMA half 1 ----
    #pragma unroll
    for (int mi = 0; mi < 4; mi++) {
      afA[mi][0] = *(const bf16x8*)(Ab + mi * 2048 + gk0);
      afA[mi][1] = *(const bf16x8*)(Ab + mi * 2048 + gk1);
    }
    #pragma unroll
    for (int ni = 0; ni < 2; ni++) {
      bq0[ni][0] = *(const bf16x8*)(Bb + ni * 2048 + gk0);
      bq0[ni][1] = *(const bf16x8*)(Bb + ni * 2048 + gk1);
      bq1[ni][0] = *(const bf16x8*)(Bb + (2 + ni) * 2048 + gk0);
      bq1[ni][1] = *(const bf16x8*)(Bb + (2 + ni) * 2048 + gk1);
    }
    asm volatile("s_waitcnt lgkmcnt(0)" ::: "memory");
    __builtin_amdgcn_sched_barrier(0);
    __builtin_amdgcn_s_setprio(1);
    #pragma unroll
    for (int kk = 0; kk < 2; kk++)
      #pragma unroll
      for (int mi = 0; mi < 4; mi++)
        #pragma unroll
        for (int ni = 0; ni < 2; ni++)
          acc[mi][ni] = __builtin_amdgcn_mfma_f32_16x16x32_bf16(afA[mi][kk], bq0[ni][kk], acc[mi][ni], 0, 0, 0);
    __builtin_amdgcn_s_setprio(0);
    BAR();   // all waves' reads of buf (t&1) complete before this point

    // ---- Ph2: stage tile t+2 into buf (t&1); MFMA half 2 ----
    if (t <= NKT - 3) { stA(t + 2); stB(t + 2); }
    __builtin_amdgcn_s_setprio(1);
    #pragma unroll
    for (int kk = 0; kk < 2; kk++)
      #pragma unroll
      for (int mi = 0; mi < 4; mi++)
        #pragma unroll
        for (int ni = 0; ni < 2; ni++)
          acc[mi][2 + ni] = __builtin_amdgcn_mfma_f32_16x16x32_bf16(afA[mi][kk], bq1[ni][kk], acc[mi][2 + ni], 0, 0, 0);
    __builtin_amdgcn_s_setprio(0);
    if (t <= NKT - 3)      asm volatile("s_waitcnt vmcnt(8)" ::: "memory");
    else if (t == NKT - 2) asm volatile("s_waitcnt vmcnt(0)" ::: "memory");
    BAR();
  }

  float bcol[4];
  #pragma unroll
  for (int ni = 0; ni < 4; ni++)
    bcol[ni] = bias[(size_t)e * DMODEL + n0 + wc + ni * 16 + fr];
  #pragma unroll
  for (int mi = 0; mi < 4; mi++) {
    #pragma unroll
    for (int r = 0; r < 4; r++) {
      int grow = m0 + wr + mi * 16 + fg * 4 + r;
      if (grow >= ce) continue;
      size_t orow = (mode == 0) ? (size_t)(oe + grow)
                                : (size_t)rowlist[e * CAP + grow];
      __bf16* op = out + orow * DMODEL + n0 + wc + fr;
      #pragma unroll
      for (int ni = 0; ni < 4; ni++) {
        float v = acc[mi][ni][r] + bcol[ni];
        if (mode == 0) v = fmaxf(v, 0.f);
        op[ni * 16] = (__bf16)v;
      }
    }
  }
}

// ---------------- combine: out[n] = s0*y[2n] + s1*y[2n+1] ----------------
__global__ __launch_bounds__(256) void combine_kernel(const __bf16* __restrict__ y,
                                                      const float* __restrict__ sco,
                                                      float* __restrict__ out) {
  int n = blockIdx.x;
  int d = threadIdx.x * 4;
  float s0 = sco[2 * n], s1 = sco[2 * n + 1];
  ushort4 a = *(const ushort4*)((const unsigned short*)(y + (size_t)(2 * n) * DMODEL + d));
  ushort4 b = *(const ushort4*)((const unsigned short*)(y + (size_t)(2 * n + 1) * DMODEL + d));
  float4 o;
  o.x = s0 * bfbits2f(a.x) + s1 * bfbits2f(b.x);
  o.y = s0 * bfbits2f(a.y) + s1 * bfbits2f(b.y);
  o.z = s0 * bfbits2f(a.z) + s1 * bfbits2f(b.z);
  o.w = s0 * bfbits2f(a.w) + s1 * bfbits2f(b.w);
  *(float4*)(out + (size_t)n * DMODEL + d) = o;
}

extern "C" void kernel_launch(void* const* d_in, const int* in_sizes, int n_in,
                              void* d_out, int out_size, void* d_ws, size_t ws_size,
                              hipStream_t stream) {
  const float* moe = (const float*)d_in[0];
  const float* gw  = (const float*)d_in[1];
  const float* gb  = (const float*)d_in[2];
  const float* rw  = (const float*)d_in[3];
  const float* rb  = (const float*)d_in[4];
  const float* W1  = (const float*)d_in[5];
  const float* b1  = (const float*)d_in[6];
  const float* W2  = (const float*)d_in[7];
  const float* b2  = (const float*)d_in[8];
  float* out = (float*)d_out;

  char* p = (char*)d_ws;
  __bf16* Xb   = (__bf16*)p; p += (size_t)N_TOK * DMODEL * 2;
  __bf16* W1bt = (__bf16*)p; p += (size_t)EXP * DMODEL * DMODEL * 2;
  __bf16* W2bt = (__bf16*)p; p += (size_t)EXP * DMODEL * DMODEL * 2;
  __bf16* hbuf = (__bf16*)p; p += (size_t)TT * DMODEL * 2;
  __bf16* ybuf = (__bf16*)p; p += (size_t)TT * DMODEL * 2;
  int*   idxb   = (int*)p;   p += (size_t)TT * 4;
  float* scoreb = (float*)p; p += (size_t)TT * 4;
  int*   rowlist = (int*)p;  p += (size_t)EXP * CAP * 4;
  int*   cntb    = (int*)p;  p += 64;
  int*   offb    = (int*)p;  p += 64;

  prep_kernel<<<dim3(9216), dim3(256), 0, stream>>>(W1, W2, W1bt, W2bt,
                                                    moe, gw, gb, rw, rb,
                                                    idxb, scoreb, Xb);
  scan_kernel<<<dim3(1), dim3(1024), 0, stream>>>(idxb, scoreb, rowlist, cntb, offb);
  moe_gemm<<<dim3(512, 8), dim3(256), 0, stream>>>(Xb, W1bt, b1, hbuf, rowlist, cntb, offb, 0);
  moe_gemm<<<dim3(512, 8), dim3(256), 0, stream>>>(hbuf, W2bt, b2, ybuf, rowlist, cntb, offb, 1);
  combine_kernel<<<dim3(16384), dim3(256), 0, stream>>>(ybuf, scoreb, out);
}